// Round 7
// baseline (213.504 us; speedup 1.0000x reference)
//
#include <hip/hip_runtime.h>
#include <hip/hip_bf16.h>
#include <math.h>

constexpr int B_ = 16;
constexpr int T_ = 10240;
constexpr int C_ = 256;
constexpr int KW = 10;
constexpr int L_ = 2047;
constexpr int N_ = B_ * L_;      // 32752
constexpr int KSTEPS = 12;
constexpr float EPS_ = 1e-5f;
constexpr int QSTR = 32768;      // per-k stride of transposed q (2048*16)

typedef short bf16x8 __attribute__((ext_vector_type(8)));
typedef float f32x4  __attribute__((ext_vector_type(4)));

// -------------------- fused: conv+relu+BN-stats  ∪  W-transpose --------------------
// blocks [0,256): stats over (b, 128-l tile), x held in registers (no LDS inner reads);
// blocks [256,448): wt 64x64 transpose tiles
__global__ __launch_bounds__(256) void stats_wt_kernel(
    const float* __restrict__ x, const float* __restrict__ cw, const float* __restrict__ cb,
    float* __restrict__ ssum, float* __restrict__ ssq,
    const float* __restrict__ tw, __hip_bfloat16* __restrict__ Wt)
{
    __shared__ float smem[64 * 65];
    const int bid = blockIdx.x;
    if (bid < 256) {
        const int b  = bid & 15;
        const int l0 = (bid >> 4) * 128;
        const int c  = threadIdx.x;
        float w[KW];
#pragma unroll
        for (int j = 0; j < KW; ++j) w[j] = cw[c * KW + j];
        const float bias = cb[c];
        const float* xg = x + (size_t)b * T_ + l0 * 5;
        const int xlim = 10236 - 5 * l0;          // last valid 4-float read start (rel)
        float s = 0.f, s2 = 0.f;
        for (int ci = 0; ci < 16; ++ci) {
            float xr[48];
#pragma unroll
            for (int u = 0; u < 12; ++u) {
                int o = min(40 * ci + 4 * u, xlim);
                *(float4*)&xr[u * 4] = *(const float4*)(xg + o);
            }
#pragma unroll
            for (int i = 0; i < 8; ++i) {
                int l = l0 + ci * 8 + i;
                float v = bias;
#pragma unroll
                for (int j = 0; j < KW; ++j) v = fmaf(xr[5 * i + j], w[j], v);
                v = fmaxf(v, 0.f);
                if (l < L_) { s += v; s2 = fmaf(v, v, s2); }
            }
        }
        atomicAdd(&ssum[c], s);
        atomicAdd(&ssq[c], s2);
    } else {
        const int idx = bid - 256;            // 0..191
        const int k  = idx >> 4;
        const int c0 = ((idx & 15) >> 2) * 64, j0 = (idx & 3) * 64;
        float (*tile)[65] = (float(*)[65])smem;
        for (int i = threadIdx.x; i < 64 * 64; i += 256) {
            int c = i >> 6, j = i & 63;
            tile[c][j] = tw[((size_t)k * C_ + (c0 + c)) * C_ + j0 + j];
        }
        __syncthreads();
        for (int i = threadIdx.x; i < 64 * 64; i += 256) {
            int j = i >> 6, c = i & 63;
            Wt[((size_t)k * C_ + (j0 + j)) * C_ + c0 + c] = __float2bfloat16(tile[c][j]);
        }
    }
}

// ---- conv+relu+normalize (BN finalize inlined) → out0 (f32 float4) + Zb (bf16) ----
__global__ __launch_bounds__(256) void conv_norm_kernel(
    const float* __restrict__ x, const float* __restrict__ cw, const float* __restrict__ cb,
    const float* __restrict__ ssum, const float* __restrict__ ssq,
    const float* __restrict__ gamma, const float* __restrict__ beta,
    __hip_bfloat16* __restrict__ Zb, float* __restrict__ out0)
{
    const int b  = blockIdx.y;
    const int l0 = blockIdx.x * 32;
    const int c  = threadIdx.x;
    __shared__ float zt2[256][33];

    float w[KW];
#pragma unroll
    for (int j = 0; j < KW; ++j) w[j] = cw[c * KW + j];
    const float bias = cb[c];
    const float inv_n = 1.0f / (float)N_;
    const float mu  = ssum[c] * inv_n;
    const float var = ssq[c] * inv_n - mu * mu;
    const float sc  = gamma[c] * rsqrtf(var + EPS_);
    const float sh  = beta[c] - mu * sc;

    const float* xg = x + (size_t)b * T_ + l0 * 5;
    const int xlim = 10236 - 5 * l0;
#pragma unroll
    for (int ci = 0; ci < 4; ++ci) {
        float xr[48];
#pragma unroll
        for (int u = 0; u < 12; ++u) {
            int o = min(40 * ci + 4 * u, xlim);
            *(float4*)&xr[u * 4] = *(const float4*)(xg + o);
        }
#pragma unroll
        for (int i = 0; i < 8; ++i) {
            int l = l0 + ci * 8 + i;
            float v = bias;
#pragma unroll
            for (int j = 0; j < KW; ++j) v = fmaf(xr[5 * i + j], w[j], v);
            v = fmaxf(v, 0.f);
            float z = fmaf(v, sc, sh);
            if (l < L_) Zb[((size_t)(b * L_ + l)) * C_ + c] = __float2bfloat16(z);
            zt2[c][ci * 8 + i] = z;
        }
    }
    __syncthreads();
    // out0: thread → (c-row, l-quad); per instr: 8 c-rows × 128B contiguous segments
    const int q4 = threadIdx.x & 7;
    const int cb0 = threadIdx.x >> 3;     // 0..31
    const int lb = l0 + q4 * 4;
#pragma unroll
    for (int i = 0; i < 8; ++i) {
        int cr = cb0 + 32 * i;
        float4 v;
        v.x = zt2[cr][q4 * 4 + 0];
        v.y = zt2[cr][q4 * 4 + 1];
        v.z = zt2[cr][q4 * 4 + 2];
        v.w = zt2[cr][q4 * 4 + 3];
        float* op = out0 + ((size_t)(b * C_ + cr)) * L_ + lb;
        if (lb + 3 < L_) *(float4*)op = v;
        else {
            if (lb     < L_) op[0] = v.x;
            if (lb + 1 < L_) op[1] = v.y;
            if (lb + 2 < L_) op[2] = v.z;
        }
    }
}

// -------------------- q kernel (MFMA, W-resident, swizzled LDS, 1 barrier/tile) ------
// q_k[i] = rowsum((Z W_k + b) ⊙ Z).  Grid (256,12): block = one k, 4 tiles × 32 rows.
// 4 waves × 64 cols (W in 128 VGPRs). LDS Z-tile: unpadded 512B rows, 16B chunk j of
// row r stored at j ^ (r&7).
__global__ __launch_bounds__(256, 2) void qmfma_kernel(
    const __hip_bfloat16* __restrict__ Zb, const __hip_bfloat16* __restrict__ Wt,
    const float* __restrict__ tb, float* __restrict__ qt)
{
    const int k   = blockIdx.y;
    const int grp = blockIdx.x;
    const __hip_bfloat16* __restrict__ Wk = Wt + (size_t)k * C_ * C_;

    __shared__ __hip_bfloat16 zs[2][32 * 256];
    __shared__ float qacc[4][128];

    const int tid  = threadIdx.x;
    const int lane = tid & 63, wave = tid >> 6;
    const int n16  = lane & 15, quad = lane >> 4;
    const int sw   = n16 & 7;

    // ---- W resident: col = 64*wave + ct*16 + n16 ; kk = it*32 + quad*8 + j ----
    bf16x8 wfrag[4][8];
    {
        const __hip_bfloat16* wb = Wk + ((size_t)(64 * wave + n16)) * C_ + quad * 8;
#pragma unroll
        for (int ct = 0; ct < 4; ++ct)
#pragma unroll
            for (int it = 0; it < 8; ++it)
                wfrag[ct][it] = *(const bf16x8*)(wb + ct * 16 * C_ + it * 32);
    }
    float4 bias4[4];
#pragma unroll
    for (int ct = 0; ct < 4; ++ct)
        bias4[ct] = *(const float4*)(tb + k * C_ + 64 * wave + ct * 16 + quad * 4);

    const int row0 = grp * 128;
    float4 greg[4];

    // stage tile 0 (32 rows × 512B, swizzled)
#pragma unroll
    for (int i = 0; i < 4; ++i) {
        int chunk = tid + i * 256;
        int r = chunk >> 5;
        int rg = row0 + r; if (rg > N_ - 1) rg = N_ - 1;
        greg[i] = *(const float4*)(Zb + (size_t)rg * C_ + (chunk & 31) * 8);
    }
#pragma unroll
    for (int i = 0; i < 4; ++i) {
        int chunk = tid + i * 256;
        int r = chunk >> 5, j = chunk & 31;
        *(float4*)((__hip_bfloat16*)zs[0] + r * 256 + (j ^ (r & 7)) * 8) = greg[i];
    }
    __syncthreads();

    for (int t = 0; t < 4; ++t) {
        const int p = t & 1;

        if (t < 3) {
            int r0 = row0 + (t + 1) * 32;
#pragma unroll
            for (int i = 0; i < 4; ++i) {
                int chunk = tid + i * 256;
                int r = chunk >> 5;
                int rg = r0 + r; if (rg > N_ - 1) rg = N_ - 1;
                greg[i] = *(const float4*)(Zb + (size_t)rg * C_ + (chunk & 31) * 8);
            }
        }

        f32x4 acc[2][4];
#pragma unroll
        for (int rt = 0; rt < 2; ++rt)
#pragma unroll
            for (int ct = 0; ct < 4; ++ct) acc[rt][ct] = f32x4{0.f, 0.f, 0.f, 0.f};

        const __hip_bfloat16* zsp = (const __hip_bfloat16*)zs[p];
#pragma unroll
        for (int it = 0; it < 8; ++it) {
            const int js = (it * 4 + quad) ^ sw;
            bf16x8 zf0 = *(const bf16x8*)(zsp + n16 * 256 + js * 8);
            bf16x8 zf1 = *(const bf16x8*)(zsp + (n16 + 16) * 256 + js * 8);
#pragma unroll
            for (int ct = 0; ct < 4; ++ct) {
                acc[0][ct] = __builtin_amdgcn_mfma_f32_16x16x32_bf16(
                    wfrag[ct][it], zf0, acc[0][ct], 0, 0, 0);
                acc[1][ct] = __builtin_amdgcn_mfma_f32_16x16x32_bf16(
                    wfrag[ct][it], zf1, acc[1][ct], 0, 0, 0);
            }
        }

        // ---- epilogue: zrow = rt*16+n16 ; wcols = 64w + ct*16 + quad*4 + r ----
#pragma unroll
        for (int rt = 0; rt < 2; ++rt) {
            const int row = rt * 16 + n16;
            float s = 0.f;
#pragma unroll
            for (int ct = 0; ct < 4; ++ct) {
                const int j  = 8 * wave + 2 * ct + (quad >> 1);
                const char* zp = (const char*)zsp + row * 512 + ((j ^ sw) << 4) + (quad & 1) * 8;
                uint2 zz = *(const uint2*)zp;
                float z0 = __uint_as_float(zz.x << 16);
                float z1 = __uint_as_float(zz.x & 0xffff0000u);
                float z2 = __uint_as_float(zz.y << 16);
                float z3 = __uint_as_float(zz.y & 0xffff0000u);
                s = fmaf(acc[rt][ct][0] + bias4[ct].x, z0, s);
                s = fmaf(acc[rt][ct][1] + bias4[ct].y, z1, s);
                s = fmaf(acc[rt][ct][2] + bias4[ct].z, z2, s);
                s = fmaf(acc[rt][ct][3] + bias4[ct].w, z3, s);
            }
            s += __shfl_xor(s, 16);
            s += __shfl_xor(s, 32);
            if (lane < 16) qacc[wave][t * 32 + row] = s;
        }

        if (t < 3) {
#pragma unroll
            for (int i = 0; i < 4; ++i) {
                int chunk = tid + i * 256;
                int r = chunk >> 5, j = chunk & 31;
                *(float4*)((__hip_bfloat16*)zs[1 - p] + r * 256 + (j ^ (r & 7)) * 8) = greg[i];
            }
        }
        __syncthreads();
    }

    // ---- block-end: reduce 4 wave partials per row, write transposed qt ----
    if (tid < 128) {
        int rg = row0 + tid;
        if (rg < N_) {
            float qv = qacc[0][tid] + qacc[1][tid] + qacc[2][tid] + qacc[3][tid];
            int b = rg / L_;
            int l = rg - b * L_;
            qt[(size_t)k * QSTR + (l << 4) + b] = qv;
        }
    }
}

// -------------------- loss: coalesced gathers from transposed q, LSE, accumulate ------
__global__ __launch_bounds__(256) void loss_kernel(
    const float* __restrict__ qt, const int* __restrict__ perm, float* __restrict__ lacc)
{
    const int k = blockIdx.y + 1;                 // 1..12
    const float* qk = qt + (size_t)(k - 1) * QSTR;
    const int nval = B_ * (L_ - k);
    const int idx = blockIdx.x * 256 + threadIdx.x;

    float contrib = 0.f;
    if (idx < nval) {
        int b = idx & 15;
        int l = k + (idx >> 4);
        float f0 = qk[(l << 4) | b];
        int pl = perm[l];
        const float* qn = qk + ((size_t)pl << 4);
        float f[10];
#pragma unroll
        for (int n = 0; n < 10; ++n) f[n] = qn[(b + 15 - n) & 15];
        float m = f0;
#pragma unroll
        for (int i = 0; i < 10; ++i) m = fmaxf(m, f[i]);
        float se = expf(f0 - m), fs = f0;
#pragma unroll
        for (int i = 0; i < 10; ++i) { se += expf(f[i] - m); fs += f[i]; }
        contrib = 11.f * (m + logf(se)) - fs;
    }

    __shared__ float red[4];
#pragma unroll
    for (int off = 32; off > 0; off >>= 1) contrib += __shfl_down(contrib, off);
    const int lane = threadIdx.x & 63;
    const int wave = threadIdx.x >> 6;
    if (lane == 0) red[wave] = contrib;
    __syncthreads();
    if (threadIdx.x == 0) atomicAdd(&lacc[k - 1], red[0] + red[1] + red[2] + red[3]);
}

__global__ void finalize_loss_kernel(const float* __restrict__ lacc, float* __restrict__ out1)
{
    int k = threadIdx.x;
    if (k < KSTEPS) {
        float div = (float)((L_ - 2 * (k + 1)) * B_);
        out1[k] = lacc[k] / div;
    }
}

// -------------------- launch --------------------
extern "C" void kernel_launch(void* const* d_in, const int* in_sizes, int n_in,
                              void* d_out, int out_size, void* d_ws, size_t ws_size,
                              hipStream_t stream)
{
    const float* x     = (const float*)d_in[0];
    const float* cw    = (const float*)d_in[1];
    const float* cb    = (const float*)d_in[2];
    const float* gamma = (const float*)d_in[3];
    const float* beta  = (const float*)d_in[4];
    const float* tw    = (const float*)d_in[5];
    const float* tb    = (const float*)d_in[6];
    const int*   perm  = (const int*)d_in[7];

    float* out0 = (float*)d_out;
    float* out1 = out0 + (size_t)B_ * C_ * L_;

    char* ws = (char*)d_ws;
    __hip_bfloat16* Zb = (__hip_bfloat16*)ws;   ws += (size_t)N_ * C_ * 2;
    __hip_bfloat16* Wt = (__hip_bfloat16*)ws;   ws += (size_t)KSTEPS * C_ * C_ * 2;
    float* qt    = (float*)ws;                  ws += (size_t)KSTEPS * QSTR * 4;
    float* ssum  = (float*)ws;                  ws += C_ * 4;
    float* ssq   = (float*)ws;                  ws += C_ * 4;
    float* lacc  = (float*)ws;                  ws += 64 * 4;

    hipMemsetAsync(ssum, 0, (C_ + C_ + 64) * sizeof(float), stream);

    stats_wt_kernel<<<448, 256, 0, stream>>>(x, cw, cb, ssum, ssq, tw, Wt);

    dim3 gcv(64, 16);
    conv_norm_kernel<<<gcv, 256, 0, stream>>>(x, cw, cb, ssum, ssq, gamma, beta, Zb, out0);

    dim3 gq(256, KSTEPS);
    qmfma_kernel<<<gq, 256, 0, stream>>>(Zb, Wt, tb, qt);

    dim3 gl(128, KSTEPS);
    loss_kernel<<<gl, 256, 0, stream>>>(qt, perm, lacc);
    finalize_loss_kernel<<<1, 64, 0, stream>>>(lacc, out1);
}